// Round 2
// baseline (1009.181 us; speedup 1.0000x reference)
//
#include <hip/hip_runtime.h>

// ---------------------------------------------------------------------------
// SRU LM: emb-gather -> SRU(512->1024,k4) -> 4x SRU(1024,k3) -> SRU(1024->512,k4)
//         -> logits = h @ emb^T + bias
// L=128 B=32 E=512 D=1024 V=32000 MID=4
// GEMM: 256x256 8-phase bf16 MFMA template (T2 swizzle + T3/T4 counted vmcnt
//       + T5 setprio + T1 XCD swizzle), C = A(M,K) * B^T(N,K), fp32 accum.
// U scratch lives in d_out (written last by the logits GEMM).
// ---------------------------------------------------------------------------

typedef __attribute__((ext_vector_type(8))) __bf16 bf16x8;
typedef __attribute__((ext_vector_type(4))) float f32x4;
typedef __attribute__((ext_vector_type(4))) float float4v;
typedef __attribute__((ext_vector_type(4))) unsigned short u16x4;

__device__ __forceinline__ unsigned short f2bf(float f) {
  unsigned int u = __builtin_bit_cast(unsigned int, f);
  u += 0x7fffu + ((u >> 16) & 1u);          // RNE
  return (unsigned short)(u >> 16);
}
__device__ __forceinline__ float bf2f(unsigned short v) {
  unsigned int u = ((unsigned int)v) << 16;
  return __builtin_bit_cast(float, u);
}

#define GLDS16(SRC, DST)                                                      \
  __builtin_amdgcn_global_load_lds(                                           \
      (__attribute__((address_space(1))) void*)(SRC),                         \
      (__attribute__((address_space(3))) void*)(DST), 16, 0, 0)

// Stage one 256x64 bf16 operand tile (A or B) into LDS.
// LDS layout: [row][slot] linear, where stored slot s holds global 16B-slot
// s ^ (row&7)  (both-sides swizzle: pre-swizzled global src, linear LDS dest).
// 4 x global_load_lds (each: 512 thr x 16 B = 64 rows).
__device__ __forceinline__ void stage_tile(const unsigned short* __restrict__ G,
                                           unsigned short* lds_tile,
                                           int row0, size_t ldK, int k0,
                                           int w, int srow, int sslot) {
#pragma unroll
  for (int j = 0; j < 4; ++j) {
    const unsigned short* src =
        G + (size_t)(row0 + j * 64 + w * 8 + srow) * ldK + k0 + sslot * 8;
    GLDS16(src, lds_tile + j * 4096 + w * 512);
  }
}

// ---------------------------------------------------------------------------
// 256x256-tile 8-phase GEMM.  C[m][n] = sum_k A[m][k]*B[n][k] (+bias[n]).
// A:(M,K) bf16, B:(N,K) bf16, C:(M,N) fp32.  M%256==0, N%256==0, K%64==0,
// K/64 >= 3.  512 threads = 8 waves (2M x 4N), per-wave 128x64 output.
// Per K-tile: 4 phases x {ds_read frags; barrier; lgkmcnt(0); 16 MFMA; barrier}
// Boundary: stage tile t+2 into freed buffer, s_waitcnt vmcnt(8) (counted).
// ---------------------------------------------------------------------------
__global__ __launch_bounds__(512, 2)
void gemm256(const unsigned short* __restrict__ A,
             const unsigned short* __restrict__ B,
             float* __restrict__ C, const float* __restrict__ bias,
             int M, int N, int K) {
  __shared__ __align__(16) unsigned short lds[2][2][16384];  // [buf][A/B][256*64]

  const int tid  = threadIdx.x;
  const int lane = tid & 63;
  const int w    = tid >> 6;
  const int wm = w >> 2, wn = w & 3;

  // bijective XCD swizzle (grid % 8 == 0 for all our shapes)
  const int nwg  = gridDim.x;
  const int orig = blockIdx.x;
  const int wg   = (orig & 7) * (nwg >> 3) + (orig >> 3);
  const int nbx  = N >> 8;
  const int bx = wg % nbx, by = wg / nbx;
  const int m0 = by * 256, n0 = bx * 256;

  const int srow  = lane >> 3;
  const int sslot = (lane & 7) ^ srow;
  const int fr = lane & 15;
  const int lg = lane >> 4;

  f32x4 acc[8][4] = {};

  const int NT = K >> 6;

  // prologue: stage tiles 0 and 1
  stage_tile(A, &lds[0][0][0], m0, K, 0,  w, srow, sslot);
  stage_tile(B, &lds[0][1][0], n0, K, 0,  w, srow, sslot);
  stage_tile(A, &lds[1][0][0], m0, K, 64, w, srow, sslot);
  stage_tile(B, &lds[1][1][0], n0, K, 64, w, srow, sslot);
  asm volatile("s_waitcnt vmcnt(8)" ::: "memory");   // tile0 landed
  __builtin_amdgcn_s_barrier();

  int cur = 0;
  for (int t = 0; t < NT; ++t) {
    const unsigned short* As = &lds[cur][0][0];
    const unsigned short* Bs = &lds[cur][1][0];
    bf16x8 bfr[2][4];
#pragma unroll
    for (int q = 0; q < 4; ++q) {
      if (q == 0) {
#pragma unroll
        for (int kk = 0; kk < 2; ++kk)
#pragma unroll
          for (int n = 0; n < 4; ++n) {
            const int row  = wn * 64 + n * 16 + fr;
            const int slot = (kk * 4 + lg) ^ (row & 7);
            bfr[kk][n] = *(const bf16x8*)&Bs[row * 64 + slot * 8];
          }
      }
      bf16x8 afr[2][2];
#pragma unroll
      for (int kk = 0; kk < 2; ++kk)
#pragma unroll
        for (int i = 0; i < 2; ++i) {
          const int row  = wm * 128 + (q * 2 + i) * 16 + fr;
          const int slot = (kk * 4 + lg) ^ (row & 7);
          afr[kk][i] = *(const bf16x8*)&As[row * 64 + slot * 8];
        }
      __builtin_amdgcn_s_barrier();
      asm volatile("s_waitcnt lgkmcnt(0)" ::: "memory");
      __builtin_amdgcn_sched_barrier(0);
      __builtin_amdgcn_s_setprio(1);
#pragma unroll
      for (int kk = 0; kk < 2; ++kk)
#pragma unroll
        for (int i = 0; i < 2; ++i)
#pragma unroll
          for (int n = 0; n < 4; ++n)
            acc[q * 2 + i][n] = __builtin_amdgcn_mfma_f32_16x16x32_bf16(
                afr[kk][i], bfr[kk][n], acc[q * 2 + i][n], 0, 0, 0);
      __builtin_amdgcn_s_setprio(0);
      __builtin_amdgcn_s_barrier();
    }
    // tile boundary: buf[cur] fully consumed -> stage tile t+2 into it,
    // then counted wait for tile t+1 (8 newest stay in flight).
    __builtin_amdgcn_sched_barrier(0);
    if (t + 2 < NT) {
      const int k2 = (t + 2) << 6;
      stage_tile(A, &lds[cur][0][0], m0, K, k2, w, srow, sslot);
      stage_tile(B, &lds[cur][1][0], n0, K, k2, w, srow, sslot);
      asm volatile("s_waitcnt vmcnt(8)" ::: "memory");
    } else {
      asm volatile("s_waitcnt vmcnt(0)" ::: "memory");
    }
    __builtin_amdgcn_s_barrier();
    __builtin_amdgcn_sched_barrier(0);
    cur ^= 1;
  }

  // epilogue: C write (+bias)
#pragma unroll
  for (int n = 0; n < 4; ++n) {
    const int col = n0 + wn * 64 + n * 16 + fr;
    const float bv = bias ? bias[col] : 0.0f;
#pragma unroll
    for (int m = 0; m < 8; ++m) {
      const int row = m0 + wm * 128 + m * 16 + lg * 4;
#pragma unroll
      for (int r = 0; r < 4; ++r)
        C[(size_t)(row + r) * N + col] = acc[m][n][r] + bv;
    }
  }
}

// ---------------------------------------------------------------------------
// SRU scan: one thread per (b,d) chain, sequential over L=128.
// ---------------------------------------------------------------------------
__global__ void scan_k(const float* __restrict__ U, const float* __restrict__ bias,
                       const float* __restrict__ c0, const unsigned short* hin,
                       unsigned short* hout, int n_out, int k) {
  const int idx = blockIdx.x * 256 + threadIdx.x;    // 0 .. 32*n_out
  const int b = idx / n_out;
  const int d = idx - b * n_out;
  const float biasf = bias[d];
  const float biasr = bias[n_out + d];
  float c = c0[idx];
  const int rowlen = k * n_out;
  const float* Up = U + (size_t)b * rowlen + d;
  const size_t lstride = (size_t)32 * rowlen;
  const unsigned short* hp = hin + (size_t)b * n_out + d;
  unsigned short* op = hout + (size_t)b * n_out + d;
  const size_t hstride = (size_t)32 * n_out;
  const bool k4 = (k == 4);
  for (int l = 0; l < 128; ++l) {
    const float xt = Up[0];
    const float fraw = Up[n_out];
    const float rraw = Up[2 * n_out];
    const float hw = k4 ? Up[3 * n_out] : bf2f(*hp);
    const float f = 1.0f / (1.0f + __expf(-(fraw + biasf)));
    const float r = 1.0f / (1.0f + __expf(-(rraw + biasr)));
    c = f * c + (1.0f - f) * xt;
    const float e2 = __expf(2.0f * c);
    const float g = 1.0f - 2.0f / (e2 + 1.0f);      // tanh(c)
    const float h = r * g + (1.0f - r) * hw;
    *op = f2bf(h);
    Up += lstride;
    hp += hstride;
    op += hstride;
  }
}

// fp32 (K,N) -> bf16 (N,K) transpose-convert.  K%32==0, N%32==0.
__global__ void transpose_k(const float* __restrict__ W,
                            unsigned short* __restrict__ Wt, int K, int N) {
  __shared__ float tile[32][33];
  const int n0 = blockIdx.x * 32, k0 = blockIdx.y * 32;
  const int tx = threadIdx.x, ty = threadIdx.y;   // (32,8)
#pragma unroll
  for (int i = 0; i < 32; i += 8)
    tile[ty + i][tx] = W[(size_t)(k0 + ty + i) * N + n0 + tx];
  __syncthreads();
#pragma unroll
  for (int i = 0; i < 32; i += 8)
    Wt[(size_t)(n0 + ty + i) * K + k0 + tx] = f2bf(tile[tx][ty + i]);
}

// fp32 -> bf16 elementwise, 4/thread
__global__ void cvt4(const float* __restrict__ in, unsigned short* __restrict__ out) {
  const int i = blockIdx.x * 256 + threadIdx.x;
  const float4v v = ((const float4v*)in)[i];
  u16x4 o;
  o.x = f2bf(v.x); o.y = f2bf(v.y); o.z = f2bf(v.z); o.w = f2bf(v.w);
  ((u16x4*)out)[i] = o;
}

// embedding gather -> bf16 (4096,512)
__global__ void embed_k(const int* __restrict__ x, const float* __restrict__ emb,
                        unsigned short* __restrict__ out) {
  const int i = blockIdx.x * 256 + threadIdx.x;   // 0..2097151
  const int row = i >> 9, e = i & 511;
  const int tok = x[row];
  out[i] = f2bf(emb[((size_t)tok << 9) + e]);
}

extern "C" void kernel_launch(void* const* d_in, const int* in_sizes, int n_in,
                              void* d_out, int out_size, void* d_ws, size_t ws_size,
                              hipStream_t stream) {
  (void)in_sizes; (void)n_in; (void)out_size; (void)ws_size;
  const int*   x     = (const int*)d_in[0];
  const float* c1    = (const float*)d_in[1];
  const float* c2    = (const float*)d_in[2];
  const float* c3    = (const float*)d_in[3];
  const float* emb   = (const float*)d_in[4];
  const float* obias = (const float*)d_in[5];
  const float* W1    = (const float*)d_in[6];
  const float* b1    = (const float*)d_in[7];
  const float* W2    = (const float*)d_in[8];
  const float* b2    = (const float*)d_in[9];
  const float* W3    = (const float*)d_in[10];
  const float* b3    = (const float*)d_in[11];

  char* ws = (char*)d_ws;
  unsigned short* hbfA  = (unsigned short*)ws;                  //  8,388,608 B
  unsigned short* hbfB  = (unsigned short*)(ws + 8388608);      //  8,388,608 B
  unsigned short* embbf = (unsigned short*)(ws + 16777216);     // 32,768,000 B
  unsigned short* Wt    = (unsigned short*)(ws + 49545216);     //  6,291,456 B
  float* U = (float*)d_out;   // up to 4096*4096 fp32 = 67 MB scratch; d_out is
                              // fully overwritten by the final logits GEMM.

  // emb -> bf16 (B-operand of logits GEMM)
  cvt4<<<16000, 256, 0, stream>>>(emb, embbf);                  // 16,384,000 elems
  // token gather -> bf16 h0 (4096 x 512)
  embed_k<<<8192, 256, 0, stream>>>(x, emb, hbfA);

  // ---- layer 1: (512 -> 1024, k=4) ----
  transpose_k<<<dim3(128, 16), dim3(32, 8), 0, stream>>>(W1, Wt, 512, 4096);
  gemm256<<<256, 512, 0, stream>>>(hbfA, Wt, U, nullptr, 4096, 4096, 512);
  scan_k<<<128, 256, 0, stream>>>(U, b1, c1, hbfB /*unused*/, hbfB, 1024, 4);

  // ---- mid layers: 4x (1024 -> 1024, k=3, hw = input) ----
  const unsigned short* hin = hbfB;
  unsigned short* hout = hbfA;
  for (int i = 0; i < 4; ++i) {
    transpose_k<<<dim3(96, 32), dim3(32, 8), 0, stream>>>(W2 + (size_t)i * 1024 * 3072,
                                                          Wt, 1024, 3072);
    gemm256<<<192, 512, 0, stream>>>(hin, Wt, U, nullptr, 4096, 3072, 1024);
    scan_k<<<128, 256, 0, stream>>>(U, b2 + i * 2048, c2 + (size_t)i * 32768,
                                    hin, hout, 1024, 3);
    const unsigned short* t = hin; hin = hout; hout = (unsigned short*)t;
  }

  // ---- final SRU: (1024 -> 512, k=4) ----
  transpose_k<<<dim3(64, 32), dim3(32, 8), 0, stream>>>(W3, Wt, 1024, 2048);
  gemm256<<<128, 512, 0, stream>>>(hin, Wt, U, nullptr, 4096, 2048, 1024);
  scan_k<<<64, 256, 0, stream>>>(U, b3, c3, hout /*unused*/, hout, 512, 4);

  // ---- logits: (4096 x 32000) = h5 @ emb^T + out_bias ----
  gemm256<<<2000, 512, 0, stream>>>(hout, embbf, (float*)d_out, obias,
                                    4096, 32000, 512);
}

// Round 3
// 697.955 us; speedup vs baseline: 1.4459x; 1.4459x over previous
//
#include <hip/hip_runtime.h>

// ---------------------------------------------------------------------------
// SRU LM: emb-gather -> SRU(512->1024,k4) -> 4x SRU(1024,k3) -> SRU(1024->512,k4)
//         -> logits = h @ emb^T + bias
// L=128 B=32 E=512 D=1024 V=32000 MID=4
// GEMM: 256x256 8-phase bf16 MFMA template (T2 swizzle + T3/T4 counted vmcnt
//       + T5 setprio + T1 XCD swizzle), C = A(M,K) * B^T(N,K), fp32 accum.
// Scans: 4-deep software-pipelined prefetch (named reg sets), template<K4>.
// Prep (emb cvt, gather, 6 weight transposes) fused into ONE kernel.
// U scratch lives in d_out (written last by the logits GEMM).
// ---------------------------------------------------------------------------

typedef __attribute__((ext_vector_type(8))) __bf16 bf16x8;
typedef __attribute__((ext_vector_type(4))) float f32x4;
typedef __attribute__((ext_vector_type(4))) float float4v;
typedef __attribute__((ext_vector_type(4))) unsigned short u16x4;

__device__ __forceinline__ unsigned short f2bf(float f) {
  unsigned int u = __builtin_bit_cast(unsigned int, f);
  u += 0x7fffu + ((u >> 16) & 1u);          // RNE
  return (unsigned short)(u >> 16);
}
__device__ __forceinline__ float bf2f(unsigned short v) {
  unsigned int u = ((unsigned int)v) << 16;
  return __builtin_bit_cast(float, u);
}

#define GLDS16(SRC, DST)                                                      \
  __builtin_amdgcn_global_load_lds(                                           \
      (__attribute__((address_space(1))) void*)(SRC),                         \
      (__attribute__((address_space(3))) void*)(DST), 16, 0, 0)

// Stage one 256x64 bf16 operand tile (A or B) into LDS.
// LDS layout: [row][slot] linear, where stored slot s holds global 16B-slot
// s ^ (row&7)  (both-sides swizzle: pre-swizzled global src, linear LDS dest).
__device__ __forceinline__ void stage_tile(const unsigned short* __restrict__ G,
                                           unsigned short* lds_tile,
                                           int row0, size_t ldK, int k0,
                                           int w, int srow, int sslot) {
#pragma unroll
  for (int j = 0; j < 4; ++j) {
    const unsigned short* src =
        G + (size_t)(row0 + j * 64 + w * 8 + srow) * ldK + k0 + sslot * 8;
    GLDS16(src, lds_tile + j * 4096 + w * 512);
  }
}

// ---------------------------------------------------------------------------
// 256x256-tile 8-phase GEMM.  C[m][n] = sum_k A[m][k]*B[n][k] (+bias[n]).
// ---------------------------------------------------------------------------
__global__ __launch_bounds__(512, 2)
void gemm256(const unsigned short* __restrict__ A,
             const unsigned short* __restrict__ B,
             float* __restrict__ C, const float* __restrict__ bias,
             int M, int N, int K) {
  __shared__ __align__(16) unsigned short lds[2][2][16384];  // [buf][A/B][256*64]

  const int tid  = threadIdx.x;
  const int lane = tid & 63;
  const int w    = tid >> 6;
  const int wm = w >> 2, wn = w & 3;

  // bijective XCD swizzle (grid % 8 == 0 for all our shapes)
  const int nwg  = gridDim.x;
  const int orig = blockIdx.x;
  const int wg   = (orig & 7) * (nwg >> 3) + (orig >> 3);
  const int nbx  = N >> 8;
  const int bx = wg % nbx, by = wg / nbx;
  const int m0 = by * 256, n0 = bx * 256;

  const int srow  = lane >> 3;
  const int sslot = (lane & 7) ^ srow;
  const int fr = lane & 15;
  const int lg = lane >> 4;

  f32x4 acc[8][4] = {};

  const int NT = K >> 6;

  // prologue: stage tiles 0 and 1
  stage_tile(A, &lds[0][0][0], m0, K, 0,  w, srow, sslot);
  stage_tile(B, &lds[0][1][0], n0, K, 0,  w, srow, sslot);
  stage_tile(A, &lds[1][0][0], m0, K, 64, w, srow, sslot);
  stage_tile(B, &lds[1][1][0], n0, K, 64, w, srow, sslot);
  asm volatile("s_waitcnt vmcnt(8)" ::: "memory");   // tile0 landed
  __builtin_amdgcn_s_barrier();

  int cur = 0;
  for (int t = 0; t < NT; ++t) {
    const unsigned short* As = &lds[cur][0][0];
    const unsigned short* Bs = &lds[cur][1][0];
    bf16x8 bfr[2][4];
#pragma unroll
    for (int q = 0; q < 4; ++q) {
      if (q == 0) {
#pragma unroll
        for (int kk = 0; kk < 2; ++kk)
#pragma unroll
          for (int n = 0; n < 4; ++n) {
            const int row  = wn * 64 + n * 16 + fr;
            const int slot = (kk * 4 + lg) ^ (row & 7);
            bfr[kk][n] = *(const bf16x8*)&Bs[row * 64 + slot * 8];
          }
      }
      bf16x8 afr[2][2];
#pragma unroll
      for (int kk = 0; kk < 2; ++kk)
#pragma unroll
        for (int i = 0; i < 2; ++i) {
          const int row  = wm * 128 + (q * 2 + i) * 16 + fr;
          const int slot = (kk * 4 + lg) ^ (row & 7);
          afr[kk][i] = *(const bf16x8*)&As[row * 64 + slot * 8];
        }
      __builtin_amdgcn_s_barrier();
      asm volatile("s_waitcnt lgkmcnt(0)" ::: "memory");
      __builtin_amdgcn_sched_barrier(0);
      __builtin_amdgcn_s_setprio(1);
#pragma unroll
      for (int kk = 0; kk < 2; ++kk)
#pragma unroll
        for (int i = 0; i < 2; ++i)
#pragma unroll
          for (int n = 0; n < 4; ++n)
            acc[q * 2 + i][n] = __builtin_amdgcn_mfma_f32_16x16x32_bf16(
                afr[kk][i], bfr[kk][n], acc[q * 2 + i][n], 0, 0, 0);
      __builtin_amdgcn_s_setprio(0);
      __builtin_amdgcn_s_barrier();
    }
    // tile boundary: buf[cur] fully consumed -> stage tile t+2 into it,
    // then counted wait for tile t+1 (8 newest stay in flight).
    __builtin_amdgcn_sched_barrier(0);
    if (t + 2 < NT) {
      const int k2 = (t + 2) << 6;
      stage_tile(A, &lds[cur][0][0], m0, K, k2, w, srow, sslot);
      stage_tile(B, &lds[cur][1][0], n0, K, k2, w, srow, sslot);
      asm volatile("s_waitcnt vmcnt(8)" ::: "memory");
    } else {
      asm volatile("s_waitcnt vmcnt(0)" ::: "memory");
    }
    __builtin_amdgcn_s_barrier();
    __builtin_amdgcn_sched_barrier(0);
    cur ^= 1;
  }

  // epilogue: C write (+bias)
#pragma unroll
  for (int n = 0; n < 4; ++n) {
    const int col = n0 + wn * 64 + n * 16 + fr;
    const float bv = bias ? bias[col] : 0.0f;
#pragma unroll
    for (int m = 0; m < 8; ++m) {
      const int row = m0 + wm * 128 + m * 16 + lg * 4;
#pragma unroll
      for (int r = 0; r < 4; ++r)
        C[(size_t)(row + r) * N + col] = acc[m][n][r] + bv;
    }
  }
}

// ---------------------------------------------------------------------------
// SRU scan, 4-deep software-pipelined.  One thread per (b,d) chain, L=128.
// U:(L,B,k*n_out) fp32. hw = U[...,3n:] if K4 else bf16 hin.  64-thr blocks.
// ---------------------------------------------------------------------------
template <bool K4>
__global__ void scan_k(const float* __restrict__ U, const float* __restrict__ bias,
                       const float* __restrict__ c0,
                       const unsigned short* __restrict__ hin,
                       unsigned short* __restrict__ hout, int n_out) {
  const int idx = blockIdx.x * 64 + threadIdx.x;     // 0 .. 32*n_out
  const int b = idx / n_out;
  const int d = idx - b * n_out;
  const float biasf = bias[d];
  const float biasr = bias[n_out + d];
  float c = c0[idx];
  const int rowlen = (K4 ? 4 : 3) * n_out;
  const float* Up = U + (size_t)b * rowlen + d;
  const size_t lstride = (size_t)32 * rowlen;
  const unsigned short* hp = hin + (size_t)b * n_out + d;
  unsigned short* op = hout + (size_t)b * n_out + d;
  const size_t hstride = (size_t)32 * n_out;

  float xt0, fr0, rr0, hw0, xt1, fr1, rr1, hw1;
  float xt2, fr2, rr2, hw2, xt3, fr3, rr3, hw3;

#define SRU_LOAD(S)                                                           \
  do {                                                                        \
    xt##S = Up[0];                                                            \
    fr##S = Up[n_out];                                                        \
    rr##S = Up[2 * n_out];                                                    \
    hw##S = K4 ? Up[3 * n_out] : bf2f(*hp);                                   \
    Up += lstride;                                                            \
    hp += hstride;                                                            \
  } while (0)

#define SRU_STEP(S)                                                           \
  do {                                                                        \
    const float f = 1.0f / (1.0f + __expf(-(fr##S + biasf)));                 \
    const float r = 1.0f / (1.0f + __expf(-(rr##S + biasr)));                 \
    c = f * c + (1.0f - f) * xt##S;                                           \
    const float e2 = __expf(2.0f * c);                                        \
    const float g = 1.0f - 2.0f / (e2 + 1.0f);                                \
    *op = f2bf(r * g + (1.0f - r) * hw##S);                                   \
    op += hstride;                                                            \
  } while (0)

  SRU_LOAD(0); SRU_LOAD(1); SRU_LOAD(2); SRU_LOAD(3);   // l = 0..3
  for (int l = 0; l < 124; l += 4) {                    // l = 0,4,...,120
    SRU_STEP(0); SRU_LOAD(0);                           // load l+4
    SRU_STEP(1); SRU_LOAD(1);
    SRU_STEP(2); SRU_LOAD(2);
    SRU_STEP(3); SRU_LOAD(3);
  }
  SRU_STEP(0); SRU_STEP(1); SRU_STEP(2); SRU_STEP(3);   // l = 124..127
#undef SRU_LOAD
#undef SRU_STEP
}

// ---------------------------------------------------------------------------
// Fused prep: emb->bf16 cvt, token gather, all 6 weight transposes.
// Range dispatch on blockIdx.x; 256 threads/block.
//   [0,16000)       cvt4   emb (16,384,000 f32 -> bf16), 4/thread
//   [16000,24192)   embed gather -> hbf0 (4096 x 512 bf16)
//   [24192,26240)   T W1  (512 x 4096)  -> W1t (4096 x 512)
//   [26240,38528)   T W2[i] (1024x3072) -> W2t+i  (3072 x 1024), 3072 blk each
//   [38528,40576)   T W3  (1024 x 2048) -> W3t (2048 x 1024)
// ---------------------------------------------------------------------------
__device__ __forceinline__ void transpose_tile(const float* __restrict__ W,
                                               unsigned short* __restrict__ Wt,
                                               int K, int N, int bx, int by,
                                               int tid) {
  __shared__ float tile[32][33];
  const int n0 = bx * 32, k0 = by * 32;
  const int tx = tid & 31, ty = tid >> 5;   // (32,8)
#pragma unroll
  for (int i = 0; i < 32; i += 8)
    tile[ty + i][tx] = W[(size_t)(k0 + ty + i) * N + n0 + tx];
  __syncthreads();
#pragma unroll
  for (int i = 0; i < 32; i += 8)
    Wt[(size_t)(n0 + ty + i) * K + k0 + tx] = f2bf(tile[tx][ty + i]);
}

__global__ void prep_k(const int* __restrict__ x, const float* __restrict__ emb,
                       const float* __restrict__ W1, const float* __restrict__ W2,
                       const float* __restrict__ W3,
                       unsigned short* __restrict__ embbf,
                       unsigned short* __restrict__ h0,
                       unsigned short* __restrict__ W1t,
                       unsigned short* __restrict__ W2t,
                       unsigned short* __restrict__ W3t) {
  const int blk = blockIdx.x;
  const int tid = threadIdx.x;
  if (blk < 16000) {                                   // cvt emb -> bf16
    const int i = blk * 256 + tid;
    const float4v v = ((const float4v*)emb)[i];
    u16x4 o;
    o.x = f2bf(v.x); o.y = f2bf(v.y); o.z = f2bf(v.z); o.w = f2bf(v.w);
    ((u16x4*)embbf)[i] = o;
  } else if (blk < 24192) {                            // embed gather
    const int i = (blk - 16000) * 256 + tid;           // 0..2097151
    const int row = i >> 9, e = i & 511;
    const int tok = x[row];
    h0[i] = f2bf(emb[((size_t)tok << 9) + e]);
  } else if (blk < 26240) {                            // W1: K=512 N=4096
    const int r = blk - 24192;                         // 128 x 16
    transpose_tile(W1, W1t, 512, 4096, r & 127, r >> 7, tid);
  } else if (blk < 38528) {                            // W2[i]: K=1024 N=3072
    const int r = (blk - 26240);
    const int i = r / 3072, rr = r - i * 3072;         // 96 x 32
    transpose_tile(W2 + (size_t)i * 3145728, W2t + (size_t)i * 3145728,
                   1024, 3072, rr % 96, rr / 96, tid);
  } else {                                             // W3: K=1024 N=2048
    const int r = blk - 38528;                         // 64 x 32
    transpose_tile(W3, W3t, 1024, 2048, r & 63, r >> 6, tid);
  }
}

extern "C" void kernel_launch(void* const* d_in, const int* in_sizes, int n_in,
                              void* d_out, int out_size, void* d_ws, size_t ws_size,
                              hipStream_t stream) {
  (void)in_sizes; (void)n_in; (void)out_size; (void)ws_size;
  const int*   x     = (const int*)d_in[0];
  const float* c1    = (const float*)d_in[1];
  const float* c2    = (const float*)d_in[2];
  const float* c3    = (const float*)d_in[3];
  const float* emb   = (const float*)d_in[4];
  const float* obias = (const float*)d_in[5];
  const float* W1    = (const float*)d_in[6];
  const float* b1    = (const float*)d_in[7];
  const float* W2    = (const float*)d_in[8];
  const float* b2    = (const float*)d_in[9];
  const float* W3    = (const float*)d_in[10];
  const float* b3    = (const float*)d_in[11];

  char* ws = (char*)d_ws;
  unsigned short* hbfA  = (unsigned short*)ws;                  //  8,388,608 B
  unsigned short* hbfB  = (unsigned short*)(ws + 8388608);      //  8,388,608 B
  unsigned short* embbf = (unsigned short*)(ws + 16777216);     // 32,768,000 B
  unsigned short* W1t   = (unsigned short*)(ws + 49545216);     //  4,194,304 B
  unsigned short* W2t   = (unsigned short*)(ws + 53739520);     // 25,165,824 B
  unsigned short* W3t   = (unsigned short*)(ws + 78905344);     //  4,194,304 B
  float* U = (float*)d_out;   // up to 4096*4096 fp32 = 67 MB scratch; d_out is
                              // fully overwritten by the final logits GEMM.

  // all input prep in one launch (cvt, gather, 6 transposes — independent)
  prep_k<<<40576, 256, 0, stream>>>(x, emb, W1, W2, W3, embbf, hbfA,
                                    W1t, W2t, W3t);

  // ---- layer 1: (512 -> 1024, k=4) ----
  gemm256<<<256, 512, 0, stream>>>(hbfA, W1t, U, nullptr, 4096, 4096, 512);
  scan_k<true><<<512, 64, 0, stream>>>(U, b1, c1, hbfB, hbfB, 1024);

  // ---- mid layers: 4x (1024 -> 1024, k=3, hw = input) ----
  const unsigned short* hin = hbfB;
  unsigned short* hout = hbfA;
  for (int i = 0; i < 4; ++i) {
    gemm256<<<192, 512, 0, stream>>>(hin, W2t + (size_t)i * 3145728, U, nullptr,
                                     4096, 3072, 1024);
    scan_k<false><<<512, 64, 0, stream>>>(U, b2 + i * 2048, c2 + (size_t)i * 32768,
                                          hin, hout, 1024);
    const unsigned short* t = hin; hin = hout; hout = (unsigned short*)t;
  }

  // ---- final SRU: (1024 -> 512, k=4) ----
  gemm256<<<128, 512, 0, stream>>>(hin, W3t, U, nullptr, 4096, 2048, 1024);
  scan_k<true><<<256, 64, 0, stream>>>(U, b3, c3, hout, hout, 512);

  // ---- logits: (4096 x 32000) = h5 @ emb^T + out_bias ----
  gemm256<<<2000, 512, 0, stream>>>(hout, embbf, (float*)d_out, obias,
                                    4096, 32000, 512);
}